// Round 2
// baseline (5167.789 us; speedup 1.0000x reference)
//
#include <hip/hip_runtime.h>
#include <stdint.h>
#include <math.h>

typedef unsigned int u32;
typedef unsigned long long u64;

#define NPX    3800        // 50*76
#define NANCH  34200       // NPX*9
#define NSEL   6000
#define NOUT   300

// ---- workspace layout (bytes) ----
// t:      [8][512][3800] f64  = 124,518,400
// wt:     [9][512][512]  f32  =   9,437,184
// boxes:  [8][34200][4]  f32  =   4,377,600
// items:  [8][34200]     u64  =   2,188,800
// sorted: [8][6000]      u32  =     192,000
#define OFF_T      0ull
#define OFF_WT     124518400ull
#define OFF_BOXES  (OFF_WT + 9437184ull)
#define OFF_ITEMS  (OFF_BOXES + 4377600ull)
#define OFF_SORTED (OFF_ITEMS + 2188800ull)

// ============================================================
// Kernel 0: weight transpose conv_w[co][ci][ky][kx] -> wt[kk][ci][co]
// ============================================================
__global__ __launch_bounds__(1024) void wtrans_kernel(const float* __restrict__ cw,
                                                      float* __restrict__ wt) {
    int o = blockIdx.x * 1024 + threadIdx.x;
    if (o >= 512*512*9) return;
    int co = o & 511;
    int ci = (o >> 9) & 511;
    int kk = o >> 18;
    wt[o] = cw[((co << 9) + ci) * 9 + kk];
}

// ============================================================
// Kernel 1: 3x3 conv 512->512 + bias + ReLU, f64 accumulation
// (f32 x f32 -> f64 product is EXACT; accumulation error ~1e-14,
//  needed because NMS pick order is chaotic w.r.t. score noise)
// tile: 128 co x 128 px, K-chunk 16, 256 threads, 8x8 f64 acc/thread
// fragment striping 2*tx + 32*j -> f64 LDS reads are 2-way (free)
// ============================================================
__global__ __launch_bounds__(256) void conv3x3_f64_kernel(const float* __restrict__ feat,
                                                          const float* __restrict__ wt,
                                                          const float* __restrict__ bias,
                                                          double* __restrict__ t) {
    const int b   = blockIdx.z;
    const int co0 = blockIdx.y * 128;
    const int p0  = blockIdx.x * 128;
    const int tid = threadIdx.x;
    const int tx  = tid & 15, ty = tid >> 4;

    __shared__ double As[16][128];   // 16 KB
    __shared__ double Bs[16][128];   // 16 KB

    double acc[8][8] = {};

    const float* featb = feat + (size_t)b * 512 * NPX;

    const int px_off = tid & 127;
    const int cbase  = (tid >> 7) << 3;    // 0 or 8
    const int p      = p0 + px_off;
    const int py     = p / 76;
    const int px     = p - py * 76;
    const bool pvalid = (p < NPX);

    for (int kk = 0; kk < 9; ++kk) {
        const int dy = kk / 3 - 1, dx = kk % 3 - 1;
        const int iy = py + dy, ix = px + dx;
        const bool ok = pvalid && ((unsigned)iy < 50u) && ((unsigned)ix < 76u);
        const float* src = featb + (size_t)iy * 76 + ix;

        for (int ci0 = 0; ci0 < 512; ci0 += 16) {
            __syncthreads();
            // ---- A tile: wt[kk][ci0..+16][co0..+128], widened to f64
            {
                const float* wsrc = wt + (((size_t)kk * 512 + ci0) << 9) + co0;
                #pragma unroll
                for (int s = 0; s < 2; ++s) {
                    int j    = tid + (s << 8);
                    int ci_r = j >> 5;
                    int co4  = (j & 31) << 2;
                    float4 v = *(const float4*)(wsrc + ((size_t)ci_r << 9) + co4);
                    As[ci_r][co4 + 0] = (double)v.x;
                    As[ci_r][co4 + 1] = (double)v.y;
                    As[ci_r][co4 + 2] = (double)v.z;
                    As[ci_r][co4 + 3] = (double)v.w;
                }
            }
            // ---- B tile: feat (zero-padded), widened to f64
            {
                #pragma unroll
                for (int s = 0; s < 8; ++s) {
                    int c = cbase + s;
                    Bs[c][px_off] = ok ? (double)src[(size_t)(ci0 + c) * NPX] : 0.0;
                }
            }
            __syncthreads();
            #pragma unroll
            for (int k = 0; k < 16; ++k) {
                double a[8], bb[8];
                #pragma unroll
                for (int i = 0; i < 4; ++i) {
                    a[2*i]    = As[k][32*i + 2*ty];
                    a[2*i+1]  = As[k][32*i + 2*ty + 1];
                    bb[2*i]   = Bs[k][32*i + 2*tx];
                    bb[2*i+1] = Bs[k][32*i + 2*tx + 1];
                }
                #pragma unroll
                for (int i = 0; i < 8; ++i)
                    #pragma unroll
                    for (int j = 0; j < 8; ++j)
                        acc[i][j] = fma(a[i], bb[j], acc[i][j]);
            }
        }
    }

    // epilogue: bias + ReLU in f64, store f64
    #pragma unroll
    for (int i = 0; i < 8; ++i) {
        int co = co0 + 32*(i >> 1) + 2*ty + (i & 1);
        double bs = (double)bias[co];
        double* row = t + ((size_t)b * 512 + co) * NPX;
        #pragma unroll
        for (int j = 0; j < 8; ++j) {
            int pp = p0 + 32*(j >> 1) + 2*tx + (j & 1);
            if (pp < NPX) {
                double v = acc[i][j] + bs;
                row[pp] = v > 0.0 ? v : 0.0;
            }
        }
    }
}

// ============================================================
// Kernel 2: fused 1x1 heads (f64) + decode + clip + minsize + sort keys
// ============================================================
__global__ __launch_bounds__(256) void heads_decode_kernel(const double* __restrict__ t,
                                                           const float* __restrict__ cls_w,
                                                           const float* __restrict__ cls_b,
                                                           const float* __restrict__ box_w,
                                                           const float* __restrict__ box_b,
                                                           float* __restrict__ out_obj,
                                                           float* __restrict__ out_del,
                                                           float* __restrict__ boxes,
                                                           u64* __restrict__ items) {
    const int b = blockIdx.y;
    const int p = blockIdx.x * 256 + threadIdx.x;
    if (p >= NPX) return;

    const double* tb = t + (size_t)b * 512 * NPX + p;

    double ac[9]  = {};
    double ab[36] = {};

    for (int ci = 0; ci < 512; ++ci) {
        double tv = tb[(size_t)ci * NPX];
        #pragma unroll
        for (int o = 0; o < 9; ++o)  ac[o] = fma((double)cls_w[o * 512 + ci], tv, ac[o]);
        #pragma unroll
        for (int o = 0; o < 36; ++o) ab[o] = fma((double)box_w[o * 512 + ci], tv, ab[o]);
    }

    float* ob = out_obj + (size_t)b * NANCH + (size_t)p * 9;
    float* dl = out_del + (size_t)b * NANCH * 4 + (size_t)p * 36;
    const int yy = p / 76, xx = p - yy * 76;

    #pragma unroll
    for (int a = 0; a < 9; ++a) {
        double s  = ac[a] + (double)cls_b[a];
        ob[a] = (float)s;
        double d0 = ab[4*a+0] + (double)box_b[4*a+0];
        double d1 = ab[4*a+1] + (double)box_b[4*a+1];
        double d2 = ab[4*a+2] + (double)box_b[4*a+2];
        double d3 = ab[4*a+3] + (double)box_b[4*a+3];
        dl[4*a+0] = (float)d0; dl[4*a+1] = (float)d1;
        dl[4*a+2] = (float)d2; dl[4*a+3] = (float)d3;

        // base anchors: f64 exact values, rounded to f32 (matches reference cast)
        int si = a / 3, ri = a - si * 3;
        double sz = (si == 0) ? 128.0 : ((si == 1) ? 256.0 : 512.0);
        double hr = (ri == 0) ? 0.7071067811865476 : ((ri == 1) ? 1.0 : 1.4142135623730951);
        float bx2f = (float)(sz / hr * 0.5);
        float by2f = (float)(sz * hr * 0.5);

        double sx = (double)(xx * 16), sy = (double)(yy * 16);
        double x1 = sx - (double)bx2f, x2 = sx + (double)bx2f;
        double y1 = sy - (double)by2f, y2 = sy + (double)by2f;

        double wa = x2 - x1, ha = y2 - y1;
        double cxa = x1 + 0.5 * wa, cya = y1 + 0.5 * ha;
        double cx = d0 * wa + cxa, cy = d1 * ha + cya;
        double w  = exp(d2) * wa,  h  = exp(d3) * ha;

        double px1 = cx - 0.5 * w, py1 = cy - 0.5 * h;
        double px2 = cx + 0.5 * w, py2 = cy + 0.5 * h;
        px1 = fmin(fmax(px1, 0.0), 1216.0);
        py1 = fmin(fmax(py1, 0.0), 800.0);
        px2 = fmin(fmax(px2, 0.0), 1216.0);
        py2 = fmin(fmax(py2, 0.0), 800.0);

        bool keep = ((px2 - px1) >= 16.0) && ((py2 - py1) >= 16.0);
        double se = keep ? s : -INFINITY;

        // f64 -> monotonic u64, descending; low 16 bits replaced by index
        u64 ubits = (u64)__double_as_longlong(se);
        u64 ka = (ubits >> 63) ? ~ubits : (ubits | 0x8000000000000000ull);
        u64 kd = ~ka;
        int n = p * 9 + a;
        items[(size_t)b * NANCH + n] = (kd & ~0xFFFFull) | (u64)(u32)n;
        *(float4*)(boxes + ((size_t)b * NANCH + n) * 4) =
            make_float4((float)px1, (float)py1, (float)px2, (float)py2);
    }
}

// ============================================================
// Kernel 3: per-image top-6000 select (2-level radix) + bitonic sort
// ============================================================
__global__ __launch_bounds__(1024) void topk_kernel(const u64* __restrict__ items,
                                                    u32* __restrict__ sorted) {
    extern __shared__ u64 buf[];              // 8192 u64 = 64 KB
    u32* hist = (u32*)buf;                    // u32[0..4095]
    u32* scan = hist + 4096;
    u32* scal = hist + 5120;

    const int b   = blockIdx.x;
    const int tid = threadIdx.x;
    const u64* it = items + (size_t)b * NANCH;

    // ---- level-1 histogram on item bits 52..63
    #pragma unroll
    for (int i = 0; i < 4; ++i) hist[tid * 4 + i] = 0;
    __syncthreads();
    for (int i = tid; i < NANCH; i += 1024)
        atomicAdd(&hist[(u32)(it[i] >> 52)], 1);
    __syncthreads();

    u32 B1, cum1;
    {
        u32 c0 = hist[tid*4], c1 = hist[tid*4+1], c2 = hist[tid*4+2], c3 = hist[tid*4+3];
        u32 S = c0 + c1 + c2 + c3;
        scan[tid] = S;
        __syncthreads();
        for (int off = 1; off < 1024; off <<= 1) {
            u32 v = (tid >= off) ? scan[tid - off] : 0;
            __syncthreads();
            scan[tid] += v;
            __syncthreads();
        }
        u32 excl = scan[tid] - S;
        const u32 target = 5999;
        if (target >= excl && target < excl + S) {
            u32 pfx = excl, bidx, cum;
            if      (target < pfx + c0)           { bidx = tid*4;   cum = pfx; }
            else if (target < pfx + c0 + c1)      { bidx = tid*4+1; cum = pfx + c0; }
            else if (target < pfx + c0 + c1 + c2) { bidx = tid*4+2; cum = pfx + c0 + c1; }
            else                                  { bidx = tid*4+3; cum = pfx + c0 + c1 + c2; }
            scal[0] = bidx; scal[1] = cum;
        }
    }
    __syncthreads();
    B1 = scal[0]; cum1 = scal[1];
    __syncthreads();

    // ---- level-2 histogram on item bits 40..51, within bin B1
    #pragma unroll
    for (int i = 0; i < 4; ++i) hist[tid * 4 + i] = 0;
    __syncthreads();
    for (int i = tid; i < NANCH; i += 1024) {
        u64 v = it[i];
        if ((u32)(v >> 52) == B1)
            atomicAdd(&hist[(u32)(v >> 40) & 0xFFF], 1);
    }
    __syncthreads();

    u32 B2;
    {
        u32 c0 = hist[tid*4], c1 = hist[tid*4+1], c2 = hist[tid*4+2], c3 = hist[tid*4+3];
        u32 S = c0 + c1 + c2 + c3;
        scan[tid] = S;
        __syncthreads();
        for (int off = 1; off < 1024; off <<= 1) {
            u32 v = (tid >= off) ? scan[tid - off] : 0;
            __syncthreads();
            scan[tid] += v;
            __syncthreads();
        }
        u32 excl = scan[tid] - S;
        const u32 target = 5999 - cum1;
        if (target >= excl && target < excl + S) {
            u32 pfx = excl, bidx;
            if      (target < pfx + c0)           bidx = tid*4;
            else if (target < pfx + c0 + c1)      bidx = tid*4+1;
            else if (target < pfx + c0 + c1 + c2) bidx = tid*4+2;
            else                                  bidx = tid*4+3;
            scal[2] = bidx;
        }
    }
    __syncthreads();
    B2 = scal[2];
    const u32 T = ((B1 << 12) | B2) + 1;
    __syncthreads();

    // ---- compaction (pad = ~0; real items have index!=0xFFFF so never ~0)
    for (int i = tid; i < 8192; i += 1024) buf[i] = ~0ull;
    __syncthreads();
    u32* cnt = (u32*)&buf[8191];
    if (tid == 0) *cnt = 0;
    __syncthreads();
    for (int i = tid; i < NANCH; i += 1024) {
        u64 v = it[i];
        if ((u32)(v >> 40) < T) {
            u32 pos = atomicAdd(cnt, 1);
            if (pos < 8191) buf[pos] = v;
        }
    }
    __syncthreads();
    if (tid == 0) buf[8191] = ~0ull;
    __syncthreads();

    // ---- bitonic sort 8192 u64 ascending (keys unique -> deterministic)
    for (int size = 2; size <= 8192; size <<= 1) {
        for (int stride = size >> 1; stride > 0; stride >>= 1) {
            #pragma unroll
            for (int v = 0; v < 4; ++v) {
                int idx = tid + (v << 10);
                int i = 2 * idx - (idx & (stride - 1));
                int j = i + stride;
                bool up = ((i & size) == 0);
                u64 x = buf[i], y = buf[j];
                if ((x > y) == up) { buf[i] = y; buf[j] = x; }
            }
            __syncthreads();
        }
    }

    // ---- emit top 6000: anchor idx (low 16 bits) + invalid flag bit 31
    for (int r = tid; r < NSEL; r += 1024) {
        u64 v = buf[r];
        u32 n = (u32)(v & 0xFFFFull);
        u32 topbits = (u32)(v >> 32);
        u32 inval = (topbits >= 0xFFF00000u) ? 0x80000000u : 0u;  // -inf/NaN score
        sorted[b * NSEL + r] = n | inval;
    }
}

// ============================================================
// Kernel 4: greedy NMS, one block/image, candidates in registers
// ============================================================
__global__ __launch_bounds__(1024) void nms_kernel(const u32* __restrict__ sorted,
                                                   const float* __restrict__ boxes,
                                                   float* __restrict__ out) {
    const int b   = blockIdx.x;
    const int tid = threadIdx.x;

    __shared__ u32 warp_min[16];
    __shared__ u32 ldsj;
    __shared__ float4 ldsbox;
    __shared__ float ldsarea;
    __shared__ u32 ldsinval;

    float4 bx[6]; float area[6]; bool alive[6]; u32 inval[6];
    #pragma unroll
    for (int s = 0; s < 6; ++s) {
        int r = tid + (s << 10);
        alive[s] = false; inval[s] = 0;
        area[s] = 0.0f; bx[s] = make_float4(0.f, 0.f, 0.f, 0.f);
        if (r < NSEL) {
            u32 e = sorted[b * NSEL + r];
            u32 n = e & 0x7FFFFFFFu;
            inval[s] = e >> 31;
            float4 v = *(const float4*)(boxes + ((size_t)b * NANCH + n) * 4);
            bx[s] = v;
            area[s] = (v.z - v.x) * (v.w - v.y);
            alive[s] = true;
        }
    }

    int nkeep = 0;
    for (int slot = 0; slot < NOUT; ++slot) {
        u32 lm = 0xFFFFFFFFu;
        #pragma unroll
        for (int s = 0; s < 6; ++s) {
            if (alive[s]) { lm = (u32)(tid + (s << 10)); break; }
        }
        #pragma unroll
        for (int off = 32; off > 0; off >>= 1) {
            u32 o = (u32)__shfl_down((int)lm, off, 64);
            lm = lm < o ? lm : o;
        }
        if ((tid & 63) == 0) warp_min[tid >> 6] = lm;
        __syncthreads();
        if (tid == 0) {
            u32 m = warp_min[0];
            #pragma unroll
            for (int w = 1; w < 16; ++w) m = m < warp_min[w] ? m : warp_min[w];
            ldsj = m;
        }
        __syncthreads();
        u32 j = ldsj;
        if (j == 0xFFFFFFFFu) break;
        if (tid == (int)(j & 1023u)) {
            int s = (int)(j >> 10);
            ldsbox = bx[s]; ldsarea = area[s]; ldsinval = inval[s];
            alive[s] = false;
        }
        __syncthreads();
        if (ldsinval) break;
        float4 P = ldsbox; float ap = ldsarea;
        if (tid == 0)
            *(float4*)(out + ((size_t)b * NOUT + slot) * 4) = P;
        #pragma unroll
        for (int s = 0; s < 6; ++s) {
            if (!alive[s]) continue;
            float ix1 = fmaxf(P.x, bx[s].x), iy1 = fmaxf(P.y, bx[s].y);
            float ix2 = fminf(P.z, bx[s].z), iy2 = fminf(P.w, bx[s].w);
            float iw = fmaxf(ix2 - ix1, 0.0f), ih = fmaxf(iy2 - iy1, 0.0f);
            float inter = iw * ih;
            float uni = ap + area[s] - inter;
            float iou = (uni > 0.0f) ? (inter / uni) : 0.0f;
            if (iou > 0.7f) alive[s] = false;
        }
        ++nkeep;
        __syncthreads();
    }

    for (int slot = nkeep + tid; slot < NOUT; slot += 1024)
        *(float4*)(out + ((size_t)b * NOUT + slot) * 4) = make_float4(0.f, 0.f, 0.f, 0.f);
}

// ============================================================
extern "C" void kernel_launch(void* const* d_in, const int* in_sizes, int n_in,
                              void* d_out, int out_size, void* d_ws, size_t ws_size,
                              hipStream_t stream) {
    const float* feat   = (const float*)d_in[0];
    const float* conv_w = (const float*)d_in[1];
    const float* conv_b = (const float*)d_in[2];
    const float* cls_w  = (const float*)d_in[3];
    const float* cls_b  = (const float*)d_in[4];
    const float* box_w  = (const float*)d_in[5];
    const float* box_b  = (const float*)d_in[6];

    float* out       = (float*)d_out;
    float* out_props = out;                       // [8][300][4]
    float* out_obj   = out + 9600;                // [8][34200]
    float* out_del   = out + 9600 + 273600;       // [8][34200][4]

    char* ws = (char*)d_ws;
    double* t      = (double*)(ws + OFF_T);
    float*  wt     = (float*)(ws + OFF_WT);
    float*  boxes  = (float*)(ws + OFF_BOXES);
    u64*    items  = (u64*)(ws + OFF_ITEMS);
    u32*    sorted = (u32*)(ws + OFF_SORTED);

    hipLaunchKernelGGL(wtrans_kernel, dim3(2304), dim3(1024), 0, stream, conv_w, wt);
    hipLaunchKernelGGL(conv3x3_f64_kernel, dim3(30, 4, 8), dim3(256), 0, stream,
                       feat, wt, conv_b, t);
    hipLaunchKernelGGL(heads_decode_kernel, dim3(15, 8), dim3(256), 0, stream,
                       t, cls_w, cls_b, box_w, box_b, out_obj, out_del, boxes, items);
    hipLaunchKernelGGL(topk_kernel, dim3(8), dim3(1024), 65536, stream, items, sorted);
    hipLaunchKernelGGL(nms_kernel, dim3(8), dim3(1024), 0, stream, sorted, boxes, out_props);
}

// Round 5
// 4133.769 us; speedup vs baseline: 1.2501x; 1.2501x over previous
//
#include <hip/hip_runtime.h>
#include <stdint.h>
#include <math.h>

typedef unsigned int u32;
typedef unsigned long long u64;
typedef double d4 __attribute__((ext_vector_type(4)));

#define NPX    3800        // 50*76
#define NANCH  34200       // NPX*9
#define NSEL   6000
#define NOUT   300

// ---- workspace layout (bytes) ---- (identical to round 2)
// t:      [8][512][3800] f64  = 124,518,400
// wt:     [9][512][512]  f32  =   9,437,184
// boxes:  [8][34200][4]  f32  =   4,377,600
// items:  [8][34200]     u64  =   2,188,800
// sorted: [8][6000]      u32  =     192,000
#define OFF_T      0ull
#define OFF_WT     124518400ull
#define OFF_BOXES  (OFF_WT + 9437184ull)
#define OFF_ITEMS  (OFF_BOXES + 4377600ull)
#define OFF_SORTED (OFF_ITEMS + 2188800ull)

// ============================================================
// Kernel 0: weight transpose conv_w[co][ci][ky][kx] -> wt[kk][ci][co]
// ============================================================
__global__ __launch_bounds__(1024) void wtrans_kernel(const float* __restrict__ cw,
                                                      float* __restrict__ wt) {
    int o = blockIdx.x * 1024 + threadIdx.x;
    if (o >= 512*512*9) return;
    int co = o & 511;
    int ci = (o >> 9) & 511;
    int kk = o >> 18;
    wt[o] = cw[((co << 9) + ci) * 9 + kk];
}

// ============================================================
// Kernel 1: 3x3 conv 512->512 + bias + ReLU via f64 MFMA
// tile: 128 co x 64 px, K-chunk 16 ci, 256 thr (4 waves)
// A/B fragment maps are dimensionally forced (A: m=lane&15,k=lane>>4;
// B: n=lane&15,k=lane>>4; quad<->ci bijection cancels since A and B
// share cf). The D lane->(row,col) map is NOT HW-verified for f64 on
// gfx950 (rounds 3/4 failed identically with the lab-notes map), so we
// PROBE it at runtime with two known-answer MFMAs and index the
// epilogue with the measured per-reg coordinates.
// ============================================================
__global__ __launch_bounds__(256, 2) void conv3x3_mfma_kernel(const float* __restrict__ feat,
                                                              const float* __restrict__ wt,
                                                              const float* __restrict__ bias,
                                                              double* __restrict__ t) {
    const int b   = blockIdx.z;
    const int co0 = blockIdx.y << 7;
    const int px0 = blockIdx.x << 6;
    const int tid = threadIdx.x;
    const int w    = tid >> 6;
    const int l    = tid & 63;
    const int quad = l >> 4;
    const int lc   = l & 15;

    __shared__ double As[16][128];   // [ci][co] 16 KB
    __shared__ double Bs[16][64];    // [ci][px]  8 KB

    // ---- runtime D-layout probe ----
    // P: A[m][k]=m, B[k][n]=1  => D[r][c] = 4r  => rr = val/4
    // Q: A[m][k]=1, B[k][n]=n  => D[r][c] = 4c  => cc = val/4
    int rr[4], cc[4];
    {
        d4 pzr = {0.0, 0.0, 0.0, 0.0};
        d4 pzc = {0.0, 0.0, 0.0, 0.0};
        double paM = (double)lc;
        double pbN = (double)lc;
        pzr = __builtin_amdgcn_mfma_f64_16x16x4f64(paM, 1.0, pzr, 0, 0, 0);
        pzc = __builtin_amdgcn_mfma_f64_16x16x4f64(1.0, pbN, pzc, 0, 0, 0);
        #pragma unroll
        for (int g = 0; g < 4; ++g) {
            rr[g] = (((int)pzr[g]) >> 2) & 15;   // clamp to tile for safety
            cc[g] = (((int)pzc[g]) >> 2) & 15;
        }
    }

    d4 acc[2][4];
    #pragma unroll
    for (int i = 0; i < 2; ++i)
        #pragma unroll
        for (int j = 0; j < 4; ++j) acc[i][j] = (d4){0.0, 0.0, 0.0, 0.0};

    const float* featb = feat + (size_t)b * 512 * NPX;

    // B staging geometry: thread covers pixel px_l, 4 ci rows
    const int px_l = tid & 63;
    const int crow = (tid >> 6) << 2;       // 0,4,8,12
    const int p    = px0 + px_l;
    const int py   = p / 76;
    const int px   = p - py * 76;
    const bool pvalid = (p < NPX);

    // A staging geometry: thread covers 8 co at one ci row
    const int a_ci = tid >> 4;              // 0..15
    const int a_co = (tid & 15) << 3;       // 0..120

    float4 va0, va1;
    float  vb[4];

    auto loadq = [&](int q) {
        int kk  = q >> 5;
        int ci0 = (q & 31) << 4;
        const float* aa = wt + (((size_t)(kk * 512 + ci0 + a_ci)) << 9) + co0 + a_co;
        va0 = *(const float4*)aa;
        va1 = *(const float4*)(aa + 4);
        int kd = kk / 3;
        int dy = kd - 1, dx = kk - kd * 3 - 1;
        int iy = py + dy, ix = px + dx;
        bool ok = pvalid && ((unsigned)iy < 50u) && ((unsigned)ix < 76u);
        if (ok) {
            const float* bb = featb + (size_t)(ci0 + crow) * NPX + iy * 76 + ix;
            #pragma unroll
            for (int s = 0; s < 4; ++s) vb[s] = bb[(size_t)s * NPX];
        } else {
            #pragma unroll
            for (int s = 0; s < 4; ++s) vb[s] = 0.0f;
        }
    };

    loadq(0);
    for (int q = 0; q < 288; ++q) {
        __syncthreads();
        As[a_ci][a_co + 0] = (double)va0.x;
        As[a_ci][a_co + 1] = (double)va0.y;
        As[a_ci][a_co + 2] = (double)va0.z;
        As[a_ci][a_co + 3] = (double)va0.w;
        As[a_ci][a_co + 4] = (double)va1.x;
        As[a_ci][a_co + 5] = (double)va1.y;
        As[a_ci][a_co + 6] = (double)va1.z;
        As[a_ci][a_co + 7] = (double)va1.w;
        Bs[crow + 0][px_l] = (double)vb[0];
        Bs[crow + 1][px_l] = (double)vb[1];
        Bs[crow + 2][px_l] = (double)vb[2];
        Bs[crow + 3][px_l] = (double)vb[3];
        __syncthreads();
        if (q < 287) loadq(q + 1);
        #pragma unroll
        for (int ks = 0; ks < 4; ++ks) {
            int cf = (ks << 2) + quad;
            double a0 = As[cf][(w << 5) + lc];
            double a1 = As[cf][(w << 5) + 16 + lc];
            #pragma unroll
            for (int nt = 0; nt < 4; ++nt) {
                double bv = Bs[cf][(nt << 4) + lc];
                acc[0][nt] = __builtin_amdgcn_mfma_f64_16x16x4f64(a0, bv, acc[0][nt], 0, 0, 0);
                acc[1][nt] = __builtin_amdgcn_mfma_f64_16x16x4f64(a1, bv, acc[1][nt], 0, 0, 0);
            }
        }
    }

    // epilogue: bias + ReLU, store f64, indexed by PROBED (rr,cc)
    #pragma unroll
    for (int mt = 0; mt < 2; ++mt) {
        #pragma unroll
        for (int g = 0; g < 4; ++g) {
            int co = co0 + (w << 5) + (mt << 4) + rr[g];
            double bs = (double)bias[co];
            double* row = t + ((size_t)b * 512 + co) * NPX;
            #pragma unroll
            for (int nt = 0; nt < 4; ++nt) {
                int pp = px0 + (nt << 4) + cc[g];
                if (pp < NPX) {
                    double v = acc[mt][nt][g] + bs;
                    row[pp] = v > 0.0 ? v : 0.0;
                }
            }
        }
    }
}

// ============================================================
// Kernel 2: fused 1x1 heads (f64) + decode + clip + minsize + sort keys
// (round-2 verbatim)
// ============================================================
__global__ __launch_bounds__(256) void heads_decode_kernel(const double* __restrict__ t,
                                                           const float* __restrict__ cls_w,
                                                           const float* __restrict__ cls_b,
                                                           const float* __restrict__ box_w,
                                                           const float* __restrict__ box_b,
                                                           float* __restrict__ out_obj,
                                                           float* __restrict__ out_del,
                                                           float* __restrict__ boxes,
                                                           u64* __restrict__ items) {
    const int b = blockIdx.y;
    const int p = blockIdx.x * 256 + threadIdx.x;
    if (p >= NPX) return;

    const double* tb = t + (size_t)b * 512 * NPX + p;

    double ac[9]  = {};
    double ab[36] = {};

    for (int ci = 0; ci < 512; ++ci) {
        double tv = tb[(size_t)ci * NPX];
        #pragma unroll
        for (int o = 0; o < 9; ++o)  ac[o] = fma((double)cls_w[o * 512 + ci], tv, ac[o]);
        #pragma unroll
        for (int o = 0; o < 36; ++o) ab[o] = fma((double)box_w[o * 512 + ci], tv, ab[o]);
    }

    float* ob = out_obj + (size_t)b * NANCH + (size_t)p * 9;
    float* dl = out_del + (size_t)b * NANCH * 4 + (size_t)p * 36;
    const int yy = p / 76, xx = p - yy * 76;

    #pragma unroll
    for (int a = 0; a < 9; ++a) {
        double s  = ac[a] + (double)cls_b[a];
        ob[a] = (float)s;
        double d0 = ab[4*a+0] + (double)box_b[4*a+0];
        double d1 = ab[4*a+1] + (double)box_b[4*a+1];
        double d2 = ab[4*a+2] + (double)box_b[4*a+2];
        double d3 = ab[4*a+3] + (double)box_b[4*a+3];
        dl[4*a+0] = (float)d0; dl[4*a+1] = (float)d1;
        dl[4*a+2] = (float)d2; dl[4*a+3] = (float)d3;

        int si = a / 3, ri = a - si * 3;
        double sz = (si == 0) ? 128.0 : ((si == 1) ? 256.0 : 512.0);
        double hr = (ri == 0) ? 0.7071067811865476 : ((ri == 1) ? 1.0 : 1.4142135623730951);
        float bx2f = (float)(sz / hr * 0.5);
        float by2f = (float)(sz * hr * 0.5);

        double sx = (double)(xx * 16), sy = (double)(yy * 16);
        double x1 = sx - (double)bx2f, x2 = sx + (double)bx2f;
        double y1 = sy - (double)by2f, y2 = sy + (double)by2f;

        double wa = x2 - x1, ha = y2 - y1;
        double cxa = x1 + 0.5 * wa, cya = y1 + 0.5 * ha;
        double cx = d0 * wa + cxa, cy = d1 * ha + cya;
        double w  = exp(d2) * wa,  h  = exp(d3) * ha;

        double px1 = cx - 0.5 * w, py1 = cy - 0.5 * h;
        double px2 = cx + 0.5 * w, py2 = cy + 0.5 * h;
        px1 = fmin(fmax(px1, 0.0), 1216.0);
        py1 = fmin(fmax(py1, 0.0), 800.0);
        px2 = fmin(fmax(px2, 0.0), 1216.0);
        py2 = fmin(fmax(py2, 0.0), 800.0);

        bool keep = ((px2 - px1) >= 16.0) && ((py2 - py1) >= 16.0);
        double se = keep ? s : -INFINITY;

        u64 ubits = (u64)__double_as_longlong(se);
        u64 ka = (ubits >> 63) ? ~ubits : (ubits | 0x8000000000000000ull);
        u64 kd = ~ka;
        int n = p * 9 + a;
        items[(size_t)b * NANCH + n] = (kd & ~0xFFFFull) | (u64)(u32)n;
        *(float4*)(boxes + ((size_t)b * NANCH + n) * 4) =
            make_float4((float)px1, (float)py1, (float)px2, (float)py2);
    }
}

// ============================================================
// Kernel 3: per-image top-6000 select (2-level radix) + bitonic sort
// (round-2 verbatim)
// ============================================================
__global__ __launch_bounds__(1024) void topk_kernel(const u64* __restrict__ items,
                                                    u32* __restrict__ sorted) {
    extern __shared__ u64 buf[];              // 8192 u64 = 64 KB
    u32* hist = (u32*)buf;
    u32* scan = hist + 4096;
    u32* scal = hist + 5120;

    const int b   = blockIdx.x;
    const int tid = threadIdx.x;
    const u64* it = items + (size_t)b * NANCH;

    #pragma unroll
    for (int i = 0; i < 4; ++i) hist[tid * 4 + i] = 0;
    __syncthreads();
    for (int i = tid; i < NANCH; i += 1024)
        atomicAdd(&hist[(u32)(it[i] >> 52)], 1);
    __syncthreads();

    u32 B1, cum1;
    {
        u32 c0 = hist[tid*4], c1 = hist[tid*4+1], c2 = hist[tid*4+2], c3 = hist[tid*4+3];
        u32 S = c0 + c1 + c2 + c3;
        scan[tid] = S;
        __syncthreads();
        for (int off = 1; off < 1024; off <<= 1) {
            u32 v = (tid >= off) ? scan[tid - off] : 0;
            __syncthreads();
            scan[tid] += v;
            __syncthreads();
        }
        u32 excl = scan[tid] - S;
        const u32 target = 5999;
        if (target >= excl && target < excl + S) {
            u32 pfx = excl, bidx, cum;
            if      (target < pfx + c0)           { bidx = tid*4;   cum = pfx; }
            else if (target < pfx + c0 + c1)      { bidx = tid*4+1; cum = pfx + c0; }
            else if (target < pfx + c0 + c1 + c2) { bidx = tid*4+2; cum = pfx + c0 + c1; }
            else                                  { bidx = tid*4+3; cum = pfx + c0 + c1 + c2; }
            scal[0] = bidx; scal[1] = cum;
        }
    }
    __syncthreads();
    B1 = scal[0]; cum1 = scal[1];
    __syncthreads();

    #pragma unroll
    for (int i = 0; i < 4; ++i) hist[tid * 4 + i] = 0;
    __syncthreads();
    for (int i = tid; i < NANCH; i += 1024) {
        u64 v = it[i];
        if ((u32)(v >> 52) == B1)
            atomicAdd(&hist[(u32)(v >> 40) & 0xFFF], 1);
    }
    __syncthreads();

    u32 B2;
    {
        u32 c0 = hist[tid*4], c1 = hist[tid*4+1], c2 = hist[tid*4+2], c3 = hist[tid*4+3];
        u32 S = c0 + c1 + c2 + c3;
        scan[tid] = S;
        __syncthreads();
        for (int off = 1; off < 1024; off <<= 1) {
            u32 v = (tid >= off) ? scan[tid - off] : 0;
            __syncthreads();
            scan[tid] += v;
            __syncthreads();
        }
        u32 excl = scan[tid] - S;
        const u32 target = 5999 - cum1;
        if (target >= excl && target < excl + S) {
            u32 pfx = excl, bidx;
            if      (target < pfx + c0)           bidx = tid*4;
            else if (target < pfx + c0 + c1)      bidx = tid*4+1;
            else if (target < pfx + c0 + c1 + c2) bidx = tid*4+2;
            else                                  bidx = tid*4+3;
            scal[2] = bidx;
        }
    }
    __syncthreads();
    B2 = scal[2];
    const u32 T = ((B1 << 12) | B2) + 1;
    __syncthreads();

    for (int i = tid; i < 8192; i += 1024) buf[i] = ~0ull;
    __syncthreads();
    u32* cnt = (u32*)&buf[8191];
    if (tid == 0) *cnt = 0;
    __syncthreads();
    for (int i = tid; i < NANCH; i += 1024) {
        u64 v = it[i];
        if ((u32)(v >> 40) < T) {
            u32 pos = atomicAdd(cnt, 1);
            if (pos < 8191) buf[pos] = v;
        }
    }
    __syncthreads();
    if (tid == 0) buf[8191] = ~0ull;
    __syncthreads();

    for (int size = 2; size <= 8192; size <<= 1) {
        for (int stride = size >> 1; stride > 0; stride >>= 1) {
            #pragma unroll
            for (int v = 0; v < 4; ++v) {
                int idx = tid + (v << 10);
                int i = 2 * idx - (idx & (stride - 1));
                int j = i + stride;
                bool up = ((i & size) == 0);
                u64 x = buf[i], y = buf[j];
                if ((x > y) == up) { buf[i] = y; buf[j] = x; }
            }
            __syncthreads();
        }
    }

    for (int r = tid; r < NSEL; r += 1024) {
        u64 v = buf[r];
        u32 n = (u32)(v & 0xFFFFull);
        u32 topbits = (u32)(v >> 32);
        u32 inval = (topbits >= 0xFFF00000u) ? 0x80000000u : 0u;
        sorted[b * NSEL + r] = n | inval;
    }
}

// ============================================================
// Kernel 4: greedy NMS, one block/image (round-2 verbatim)
// ============================================================
__global__ __launch_bounds__(1024) void nms_kernel(const u32* __restrict__ sorted,
                                                   const float* __restrict__ boxes,
                                                   float* __restrict__ out) {
    const int b   = blockIdx.x;
    const int tid = threadIdx.x;

    __shared__ u32 warp_min[16];
    __shared__ u32 ldsj;
    __shared__ float4 ldsbox;
    __shared__ float ldsarea;
    __shared__ u32 ldsinval;

    float4 bx[6]; float area[6]; bool alive[6]; u32 inval[6];
    #pragma unroll
    for (int s = 0; s < 6; ++s) {
        int r = tid + (s << 10);
        alive[s] = false; inval[s] = 0;
        area[s] = 0.0f; bx[s] = make_float4(0.f, 0.f, 0.f, 0.f);
        if (r < NSEL) {
            u32 e = sorted[b * NSEL + r];
            u32 n = e & 0x7FFFFFFFu;
            inval[s] = e >> 31;
            float4 v = *(const float4*)(boxes + ((size_t)b * NANCH + n) * 4);
            bx[s] = v;
            area[s] = (v.z - v.x) * (v.w - v.y);
            alive[s] = true;
        }
    }

    int nkeep = 0;
    for (int slot = 0; slot < NOUT; ++slot) {
        u32 lm = 0xFFFFFFFFu;
        #pragma unroll
        for (int s = 0; s < 6; ++s) {
            if (alive[s]) { lm = (u32)(tid + (s << 10)); break; }
        }
        #pragma unroll
        for (int off = 32; off > 0; off >>= 1) {
            u32 o = (u32)__shfl_down((int)lm, off, 64);
            lm = lm < o ? lm : o;
        }
        if ((tid & 63) == 0) warp_min[tid >> 6] = lm;
        __syncthreads();
        if (tid == 0) {
            u32 m = warp_min[0];
            #pragma unroll
            for (int w = 1; w < 16; ++w) m = m < warp_min[w] ? m : warp_min[w];
            ldsj = m;
        }
        __syncthreads();
        u32 j = ldsj;
        if (j == 0xFFFFFFFFu) break;
        if (tid == (int)(j & 1023u)) {
            int s = (int)(j >> 10);
            ldsbox = bx[s]; ldsarea = area[s]; ldsinval = inval[s];
            alive[s] = false;
        }
        __syncthreads();
        if (ldsinval) break;
        float4 P = ldsbox; float ap = ldsarea;
        if (tid == 0)
            *(float4*)(out + ((size_t)b * NOUT + slot) * 4) = P;
        #pragma unroll
        for (int s = 0; s < 6; ++s) {
            if (!alive[s]) continue;
            float ix1 = fmaxf(P.x, bx[s].x), iy1 = fmaxf(P.y, bx[s].y);
            float ix2 = fminf(P.z, bx[s].z), iy2 = fminf(P.w, bx[s].w);
            float iw = fmaxf(ix2 - ix1, 0.0f), ih = fmaxf(iy2 - iy1, 0.0f);
            float inter = iw * ih;
            float uni = ap + area[s] - inter;
            float iou = (uni > 0.0f) ? (inter / uni) : 0.0f;
            if (iou > 0.7f) alive[s] = false;
        }
        ++nkeep;
        __syncthreads();
    }

    for (int slot = nkeep + tid; slot < NOUT; slot += 1024)
        *(float4*)(out + ((size_t)b * NOUT + slot) * 4) = make_float4(0.f, 0.f, 0.f, 0.f);
}

// ============================================================
extern "C" void kernel_launch(void* const* d_in, const int* in_sizes, int n_in,
                              void* d_out, int out_size, void* d_ws, size_t ws_size,
                              hipStream_t stream) {
    const float* feat   = (const float*)d_in[0];
    const float* conv_w = (const float*)d_in[1];
    const float* conv_b = (const float*)d_in[2];
    const float* cls_w  = (const float*)d_in[3];
    const float* cls_b  = (const float*)d_in[4];
    const float* box_w  = (const float*)d_in[5];
    const float* box_b  = (const float*)d_in[6];

    float* out       = (float*)d_out;
    float* out_props = out;                       // [8][300][4]
    float* out_obj   = out + 9600;                // [8][34200]
    float* out_del   = out + 9600 + 273600;       // [8][34200][4]

    char* ws = (char*)d_ws;
    double* t      = (double*)(ws + OFF_T);
    float*  wt     = (float*)(ws + OFF_WT);
    float*  boxes  = (float*)(ws + OFF_BOXES);
    u64*    items  = (u64*)(ws + OFF_ITEMS);
    u32*    sorted = (u32*)(ws + OFF_SORTED);

    hipLaunchKernelGGL(wtrans_kernel, dim3(2304), dim3(1024), 0, stream, conv_w, wt);
    hipLaunchKernelGGL(conv3x3_mfma_kernel, dim3(60, 4, 8), dim3(256), 0, stream,
                       feat, wt, conv_b, t);
    hipLaunchKernelGGL(heads_decode_kernel, dim3(15, 8), dim3(256), 0, stream,
                       t, cls_w, cls_b, box_w, box_b, out_obj, out_del, boxes, items);
    hipLaunchKernelGGL(topk_kernel, dim3(8), dim3(1024), 65536, stream, items, sorted);
    hipLaunchKernelGGL(nms_kernel, dim3(8), dim3(1024), 0, stream, sorted, boxes, out_props);
}

// Round 6
// 3846.101 us; speedup vs baseline: 1.3436x; 1.0748x over previous
//
#include <hip/hip_runtime.h>
#include <stdint.h>
#include <math.h>

typedef unsigned int u32;
typedef unsigned long long u64;
typedef double d4 __attribute__((ext_vector_type(4)));

#define NPX    3800        // 50*76
#define NANCH  34200       // NPX*9
#define NSEL   6000
#define NOUT   300

// ---- workspace layout (bytes) ----
// t:      [8][512][3800] f64  = 124,518,400
// wt:     [9][512][512]  f32  =   9,437,184
// boxes:  [8][34200][4]  f32  =   4,377,600
// items:  [8][34200]     u64  =   2,188,800
// sorted: [8][6000]      u32  =     192,000
// part:   [4][8][45][3800] f64 = 43,776,000   (split-K heads, if ws permits)
#define OFF_T      0ull
#define OFF_WT     124518400ull
#define OFF_BOXES  (OFF_WT + 9437184ull)
#define OFF_ITEMS  (OFF_BOXES + 4377600ull)
#define OFF_SORTED (OFF_ITEMS + 2188800ull)
#define OFF_PART   (OFF_SORTED + 192000ull)
#define WS_NEED_SPLIT (OFF_PART + 43776000ull)

// ============================================================
// Kernel 0: weight transpose conv_w[co][ci][ky][kx] -> wt[kk][ci][co]
// ============================================================
__global__ __launch_bounds__(1024) void wtrans_kernel(const float* __restrict__ cw,
                                                      float* __restrict__ wt) {
    int o = blockIdx.x * 1024 + threadIdx.x;
    if (o >= 512*512*9) return;
    int co = o & 511;
    int ci = (o >> 9) & 511;
    int kk = o >> 18;
    wt[o] = cw[((co << 9) + ci) * 9 + kk];
}

// ============================================================
// Kernel 1: 3x3 conv 512->512 + bias + ReLU via f64 MFMA
// tile: 128 co x 64 px, K-chunk 16 ci, 256 thr (4 waves)
// LDS in FRAGMENT ORDER (round-5 had 4-way bank conflicts on every
// K-loop ds_read because cf varied with quad at 0-mod-32-bank stride):
//   AsF[frag=(ks*8 + w*2 + mt)][lane],  lane = quad*16+lc
//   BsF[frag=(ks*4 + nt)][lane]
// -> every ds_read_b64 and ds_write_b64 is lane-consecutive (conflict-free).
// D lane->coord map PROBED at runtime (this is what fixed rounds 3/4).
// ============================================================
__global__ __launch_bounds__(256, 2) void conv3x3_mfma_kernel(const float* __restrict__ feat,
                                                              const float* __restrict__ wt,
                                                              const float* __restrict__ bias,
                                                              double* __restrict__ t) {
    const int b   = blockIdx.z;
    const int co0 = blockIdx.y << 7;
    const int px0 = blockIdx.x << 6;
    const int tid = threadIdx.x;
    const int w    = tid >> 6;
    const int l    = tid & 63;
    const int lc   = l & 15;

    __shared__ double AsF[2048];   // 16 KB: 32 frags x 64 lanes
    __shared__ double BsF[1024];   //  8 KB: 16 frags x 64 lanes

    // ---- runtime D-layout probe ----
    int rr[4], cc[4];
    {
        d4 pzr = {0.0, 0.0, 0.0, 0.0};
        d4 pzc = {0.0, 0.0, 0.0, 0.0};
        double paM = (double)lc;
        double pbN = (double)lc;
        pzr = __builtin_amdgcn_mfma_f64_16x16x4f64(paM, 1.0, pzr, 0, 0, 0);
        pzc = __builtin_amdgcn_mfma_f64_16x16x4f64(1.0, pbN, pzc, 0, 0, 0);
        #pragma unroll
        for (int g = 0; g < 4; ++g) {
            rr[g] = (((int)pzr[g]) >> 2) & 15;
            cc[g] = (((int)pzc[g]) >> 2) & 15;
        }
    }

    d4 acc[2][4];
    #pragma unroll
    for (int i = 0; i < 2; ++i)
        #pragma unroll
        for (int j = 0; j < 4; ++j) acc[i][j] = (d4){0.0, 0.0, 0.0, 0.0};

    const float* featb = feat + (size_t)b * 512 * NPX;

    // A staging decomposition: slot = tid + 256*j (j=0..7), slot -> (frag,lane):
    //   frag = slot>>6 = 4j + (tid>>6);  ks=frag>>3, wa=(frag>>1)&3, mt=frag&1
    //   lane = tid&63: quad=(tid>>4)&3, lc=tid&15
    //   element: ci_local = 4*ks + quad, co = wa*32 + mt*16 + lc
    const int a_quad = (tid >> 4) & 3;
    const int a_lc   = tid & 15;
    const int a_mt   = (tid >> 6) & 1;
    const int a_whi  = tid >> 7;

    // B staging: slot = tid + 256*j (j=0..3): frag = 4j + (tid>>6) = ks*4+nt
    //   -> ks=j, nt=tid>>6, quad=(tid>>4)&3, lc=tid&15
    //   element: ci_local = 4*j + quad, px_local = nt*16 + lc  (fixed per thread)
    const int b_quad = (tid >> 4) & 3;
    const int b_pxl  = ((tid >> 6) << 4) | (tid & 15);
    const int p      = px0 + b_pxl;
    const int py     = p / 76;
    const int px     = p - py * 76;
    const bool pvalid = (p < NPX);

    float va[8], vb[4];

    auto loadq = [&](int q) {
        int kk  = q >> 5;
        int ci0 = (q & 31) << 4;
        const float* wrow = wt + (((size_t)(kk * 512 + ci0)) << 9) + co0;
        #pragma unroll
        for (int j = 0; j < 8; ++j) {
            int ks   = j >> 1;
            int wa   = ((j & 1) << 1) | a_whi;
            int ci_l = (ks << 2) | a_quad;
            int co   = (wa << 5) + (a_mt << 4) + a_lc;
            va[j] = wrow[((size_t)ci_l << 9) + co];
        }
        int kd = kk / 3;
        int dy = kd - 1, dx = kk - kd * 3 - 1;
        int iy = py + dy, ix = px + dx;
        bool ok = pvalid && ((unsigned)iy < 50u) && ((unsigned)ix < 76u);
        if (ok) {
            const float* bbp = featb + (size_t)(ci0 + b_quad) * NPX + iy * 76 + ix;
            #pragma unroll
            for (int j = 0; j < 4; ++j) vb[j] = bbp[(size_t)(j << 2) * NPX];
        } else {
            vb[0] = vb[1] = vb[2] = vb[3] = 0.0f;
        }
    };

    loadq(0);
    for (int q = 0; q < 288; ++q) {
        __syncthreads();
        #pragma unroll
        for (int j = 0; j < 8; ++j) AsF[tid + (j << 8)] = (double)va[j];
        #pragma unroll
        for (int j = 0; j < 4; ++j) BsF[tid + (j << 8)] = (double)vb[j];
        __syncthreads();
        if (q < 287) loadq(q + 1);
        #pragma unroll
        for (int ks = 0; ks < 4; ++ks) {
            const double* ap = &AsF[((ks << 3) + (w << 1)) << 6];  // frag (ks,w,mt=0)
            double a0 = ap[l];
            double a1 = ap[64 + l];                                // mt=1
            const double* bp = &BsF[ks << 8];                      // frag (ks,nt=0)
            #pragma unroll
            for (int nt = 0; nt < 4; ++nt) {
                double bv = bp[(nt << 6) + l];
                acc[0][nt] = __builtin_amdgcn_mfma_f64_16x16x4f64(a0, bv, acc[0][nt], 0, 0, 0);
                acc[1][nt] = __builtin_amdgcn_mfma_f64_16x16x4f64(a1, bv, acc[1][nt], 0, 0, 0);
            }
        }
    }

    // epilogue: bias + ReLU, store f64, indexed by PROBED (rr,cc)
    #pragma unroll
    for (int mt = 0; mt < 2; ++mt) {
        #pragma unroll
        for (int g = 0; g < 4; ++g) {
            int co = co0 + (w << 5) + (mt << 4) + rr[g];
            double bs = (double)bias[co];
            double* row = t + ((size_t)b * 512 + co) * NPX;
            #pragma unroll
            for (int nt = 0; nt < 4; ++nt) {
                int pp = px0 + (nt << 4) + cc[g];
                if (pp < NPX) {
                    double v = acc[mt][nt][g] + bs;
                    row[pp] = v > 0.0 ? v : 0.0;
                }
            }
        }
    }
}

// ============================================================
// Kernel 2a: 1x1 heads, split-K x4 partials (f64)
// part layout: [c][b][o][p] = ((c*8+b)*45+o)*NPX + p
// ============================================================
__global__ __launch_bounds__(64) void heads_partial_kernel(const double* __restrict__ t,
                                                           const float* __restrict__ cls_w,
                                                           const float* __restrict__ box_w,
                                                           double* __restrict__ part) {
    const int b = blockIdx.y, c = blockIdx.z;
    const int p = blockIdx.x * 64 + threadIdx.x;
    if (p >= NPX) return;
    const double* tb = t + ((size_t)b * 512 + c * 128) * NPX + p;

    double ac[9]  = {};
    double ab[36] = {};
    for (int ci = 0; ci < 128; ++ci) {
        double tv = tb[(size_t)ci * NPX];
        int cw = c * 128 + ci;
        #pragma unroll
        for (int o = 0; o < 9;  ++o) ac[o] = fma((double)cls_w[o * 512 + cw], tv, ac[o]);
        #pragma unroll
        for (int o = 0; o < 36; ++o) ab[o] = fma((double)box_w[o * 512 + cw], tv, ab[o]);
    }
    double* dst = part + ((size_t)(c * 8 + b) * 45) * NPX + p;
    #pragma unroll
    for (int o = 0; o < 9;  ++o) dst[(size_t)o * NPX] = ac[o];
    #pragma unroll
    for (int o = 0; o < 36; ++o) dst[(size_t)(9 + o) * NPX] = ab[o];
}

// shared decode body
__device__ __forceinline__ void decode_px(int b, int p, const double* s45,
                                          const float* cls_b, const float* box_b,
                                          float* out_obj, float* out_del,
                                          float* boxes, u64* items) {
    float* ob = out_obj + (size_t)b * NANCH + (size_t)p * 9;
    float* dl = out_del + (size_t)b * NANCH * 4 + (size_t)p * 36;
    const int yy = p / 76, xx = p - yy * 76;

    #pragma unroll
    for (int a = 0; a < 9; ++a) {
        double s  = s45[a] + (double)cls_b[a];
        ob[a] = (float)s;
        double d0 = s45[9 + 4*a + 0] + (double)box_b[4*a+0];
        double d1 = s45[9 + 4*a + 1] + (double)box_b[4*a+1];
        double d2 = s45[9 + 4*a + 2] + (double)box_b[4*a+2];
        double d3 = s45[9 + 4*a + 3] + (double)box_b[4*a+3];
        dl[4*a+0] = (float)d0; dl[4*a+1] = (float)d1;
        dl[4*a+2] = (float)d2; dl[4*a+3] = (float)d3;

        int si = a / 3, ri = a - si * 3;
        double sz = (si == 0) ? 128.0 : ((si == 1) ? 256.0 : 512.0);
        double hr = (ri == 0) ? 0.7071067811865476 : ((ri == 1) ? 1.0 : 1.4142135623730951);
        float bx2f = (float)(sz / hr * 0.5);
        float by2f = (float)(sz * hr * 0.5);

        double sx = (double)(xx * 16), sy = (double)(yy * 16);
        double x1 = sx - (double)bx2f, x2 = sx + (double)bx2f;
        double y1 = sy - (double)by2f, y2 = sy + (double)by2f;

        double wa = x2 - x1, ha = y2 - y1;
        double cxa = x1 + 0.5 * wa, cya = y1 + 0.5 * ha;
        double cx = d0 * wa + cxa, cy = d1 * ha + cya;
        double w  = exp(d2) * wa,  h  = exp(d3) * ha;

        double px1 = cx - 0.5 * w, py1 = cy - 0.5 * h;
        double px2 = cx + 0.5 * w, py2 = cy + 0.5 * h;
        px1 = fmin(fmax(px1, 0.0), 1216.0);
        py1 = fmin(fmax(py1, 0.0), 800.0);
        px2 = fmin(fmax(px2, 0.0), 1216.0);
        py2 = fmin(fmax(py2, 0.0), 800.0);

        bool keep = ((px2 - px1) >= 16.0) && ((py2 - py1) >= 16.0);
        double se = keep ? s : -INFINITY;

        u64 ubits = (u64)__double_as_longlong(se);
        u64 ka = (ubits >> 63) ? ~ubits : (ubits | 0x8000000000000000ull);
        u64 kd = ~ka;
        int n = p * 9 + a;
        items[(size_t)b * NANCH + n] = (kd & ~0xFFFFull) | (u64)(u32)n;
        *(float4*)(boxes + ((size_t)b * NANCH + n) * 4) =
            make_float4((float)px1, (float)py1, (float)px2, (float)py2);
    }
}

// ============================================================
// Kernel 2b: reduce partials (c ascending, deterministic) + decode
// ============================================================
__global__ __launch_bounds__(64) void reduce_decode_kernel(const double* __restrict__ part,
                                                           const float* __restrict__ cls_b,
                                                           const float* __restrict__ box_b,
                                                           float* __restrict__ out_obj,
                                                           float* __restrict__ out_del,
                                                           float* __restrict__ boxes,
                                                           u64* __restrict__ items) {
    const int b = blockIdx.y;
    const int p = blockIdx.x * 64 + threadIdx.x;
    if (p >= NPX) return;
    double s45[45];
    #pragma unroll
    for (int o = 0; o < 45; ++o) {
        double s = part[((size_t)(0 * 8 + b) * 45 + o) * NPX + p];
        s += part[((size_t)(1 * 8 + b) * 45 + o) * NPX + p];
        s += part[((size_t)(2 * 8 + b) * 45 + o) * NPX + p];
        s += part[((size_t)(3 * 8 + b) * 45 + o) * NPX + p];
        s45[o] = s;
    }
    decode_px(b, p, s45, cls_b, box_b, out_obj, out_del, boxes, items);
}

// ============================================================
// Kernel 2-fallback: single-stage heads+decode (if ws too small)
// ============================================================
__global__ __launch_bounds__(256) void heads_decode_kernel(const double* __restrict__ t,
                                                           const float* __restrict__ cls_w,
                                                           const float* __restrict__ cls_b,
                                                           const float* __restrict__ box_w,
                                                           const float* __restrict__ box_b,
                                                           float* __restrict__ out_obj,
                                                           float* __restrict__ out_del,
                                                           float* __restrict__ boxes,
                                                           u64* __restrict__ items) {
    const int b = blockIdx.y;
    const int p = blockIdx.x * 256 + threadIdx.x;
    if (p >= NPX) return;
    const double* tb = t + (size_t)b * 512 * NPX + p;
    double s45[45];
    #pragma unroll
    for (int o = 0; o < 45; ++o) s45[o] = 0.0;
    for (int ci = 0; ci < 512; ++ci) {
        double tv = tb[(size_t)ci * NPX];
        #pragma unroll
        for (int o = 0; o < 9;  ++o) s45[o]     = fma((double)cls_w[o * 512 + ci], tv, s45[o]);
        #pragma unroll
        for (int o = 0; o < 36; ++o) s45[9 + o] = fma((double)box_w[o * 512 + ci], tv, s45[9 + o]);
    }
    decode_px(b, p, s45, cls_b, box_b, out_obj, out_del, boxes, items);
}

// ============================================================
// Kernel 3: per-image top-6000 select (2-level radix) + bitonic sort
// (round-2 verbatim)
// ============================================================
__global__ __launch_bounds__(1024) void topk_kernel(const u64* __restrict__ items,
                                                    u32* __restrict__ sorted) {
    extern __shared__ u64 buf[];              // 8192 u64 = 64 KB
    u32* hist = (u32*)buf;
    u32* scan = hist + 4096;
    u32* scal = hist + 5120;

    const int b   = blockIdx.x;
    const int tid = threadIdx.x;
    const u64* it = items + (size_t)b * NANCH;

    #pragma unroll
    for (int i = 0; i < 4; ++i) hist[tid * 4 + i] = 0;
    __syncthreads();
    for (int i = tid; i < NANCH; i += 1024)
        atomicAdd(&hist[(u32)(it[i] >> 52)], 1);
    __syncthreads();

    u32 B1, cum1;
    {
        u32 c0 = hist[tid*4], c1 = hist[tid*4+1], c2 = hist[tid*4+2], c3 = hist[tid*4+3];
        u32 S = c0 + c1 + c2 + c3;
        scan[tid] = S;
        __syncthreads();
        for (int off = 1; off < 1024; off <<= 1) {
            u32 v = (tid >= off) ? scan[tid - off] : 0;
            __syncthreads();
            scan[tid] += v;
            __syncthreads();
        }
        u32 excl = scan[tid] - S;
        const u32 target = 5999;
        if (target >= excl && target < excl + S) {
            u32 pfx = excl, bidx, cum;
            if      (target < pfx + c0)           { bidx = tid*4;   cum = pfx; }
            else if (target < pfx + c0 + c1)      { bidx = tid*4+1; cum = pfx + c0; }
            else if (target < pfx + c0 + c1 + c2) { bidx = tid*4+2; cum = pfx + c0 + c1; }
            else                                  { bidx = tid*4+3; cum = pfx + c0 + c1 + c2; }
            scal[0] = bidx; scal[1] = cum;
        }
    }
    __syncthreads();
    B1 = scal[0]; cum1 = scal[1];
    __syncthreads();

    #pragma unroll
    for (int i = 0; i < 4; ++i) hist[tid * 4 + i] = 0;
    __syncthreads();
    for (int i = tid; i < NANCH; i += 1024) {
        u64 v = it[i];
        if ((u32)(v >> 52) == B1)
            atomicAdd(&hist[(u32)(v >> 40) & 0xFFF], 1);
    }
    __syncthreads();

    u32 B2;
    {
        u32 c0 = hist[tid*4], c1 = hist[tid*4+1], c2 = hist[tid*4+2], c3 = hist[tid*4+3];
        u32 S = c0 + c1 + c2 + c3;
        scan[tid] = S;
        __syncthreads();
        for (int off = 1; off < 1024; off <<= 1) {
            u32 v = (tid >= off) ? scan[tid - off] : 0;
            __syncthreads();
            scan[tid] += v;
            __syncthreads();
        }
        u32 excl = scan[tid] - S;
        const u32 target = 5999 - cum1;
        if (target >= excl && target < excl + S) {
            u32 pfx = excl, bidx;
            if      (target < pfx + c0)           bidx = tid*4;
            else if (target < pfx + c0 + c1)      bidx = tid*4+1;
            else if (target < pfx + c0 + c1 + c2) bidx = tid*4+2;
            else                                  bidx = tid*4+3;
            scal[2] = bidx;
        }
    }
    __syncthreads();
    B2 = scal[2];
    const u32 T = ((B1 << 12) | B2) + 1;
    __syncthreads();

    for (int i = tid; i < 8192; i += 1024) buf[i] = ~0ull;
    __syncthreads();
    u32* cnt = (u32*)&buf[8191];
    if (tid == 0) *cnt = 0;
    __syncthreads();
    for (int i = tid; i < NANCH; i += 1024) {
        u64 v = it[i];
        if ((u32)(v >> 40) < T) {
            u32 pos = atomicAdd(cnt, 1);
            if (pos < 8191) buf[pos] = v;
        }
    }
    __syncthreads();
    if (tid == 0) buf[8191] = ~0ull;
    __syncthreads();

    for (int size = 2; size <= 8192; size <<= 1) {
        for (int stride = size >> 1; stride > 0; stride >>= 1) {
            #pragma unroll
            for (int v = 0; v < 4; ++v) {
                int idx = tid + (v << 10);
                int i = 2 * idx - (idx & (stride - 1));
                int j = i + stride;
                bool up = ((i & size) == 0);
                u64 x = buf[i], y = buf[j];
                if ((x > y) == up) { buf[i] = y; buf[j] = x; }
            }
            __syncthreads();
        }
    }

    for (int r = tid; r < NSEL; r += 1024) {
        u64 v = buf[r];
        u32 n = (u32)(v & 0xFFFFull);
        u32 topbits = (u32)(v >> 32);
        u32 inval = (topbits >= 0xFFF00000u) ? 0x80000000u : 0u;
        sorted[b * NSEL + r] = n | inval;
    }
}

// ============================================================
// Kernel 4: greedy NMS, one block/image (round-2 verbatim)
// ============================================================
__global__ __launch_bounds__(1024) void nms_kernel(const u32* __restrict__ sorted,
                                                   const float* __restrict__ boxes,
                                                   float* __restrict__ out) {
    const int b   = blockIdx.x;
    const int tid = threadIdx.x;

    __shared__ u32 warp_min[16];
    __shared__ u32 ldsj;
    __shared__ float4 ldsbox;
    __shared__ float ldsarea;
    __shared__ u32 ldsinval;

    float4 bx[6]; float area[6]; bool alive[6]; u32 inval[6];
    #pragma unroll
    for (int s = 0; s < 6; ++s) {
        int r = tid + (s << 10);
        alive[s] = false; inval[s] = 0;
        area[s] = 0.0f; bx[s] = make_float4(0.f, 0.f, 0.f, 0.f);
        if (r < NSEL) {
            u32 e = sorted[b * NSEL + r];
            u32 n = e & 0x7FFFFFFFu;
            inval[s] = e >> 31;
            float4 v = *(const float4*)(boxes + ((size_t)b * NANCH + n) * 4);
            bx[s] = v;
            area[s] = (v.z - v.x) * (v.w - v.y);
            alive[s] = true;
        }
    }

    int nkeep = 0;
    for (int slot = 0; slot < NOUT; ++slot) {
        u32 lm = 0xFFFFFFFFu;
        #pragma unroll
        for (int s = 0; s < 6; ++s) {
            if (alive[s]) { lm = (u32)(tid + (s << 10)); break; }
        }
        #pragma unroll
        for (int off = 32; off > 0; off >>= 1) {
            u32 o = (u32)__shfl_down((int)lm, off, 64);
            lm = lm < o ? lm : o;
        }
        if ((tid & 63) == 0) warp_min[tid >> 6] = lm;
        __syncthreads();
        if (tid == 0) {
            u32 m = warp_min[0];
            #pragma unroll
            for (int w = 1; w < 16; ++w) m = m < warp_min[w] ? m : warp_min[w];
            ldsj = m;
        }
        __syncthreads();
        u32 j = ldsj;
        if (j == 0xFFFFFFFFu) break;
        if (tid == (int)(j & 1023u)) {
            int s = (int)(j >> 10);
            ldsbox = bx[s]; ldsarea = area[s]; ldsinval = inval[s];
            alive[s] = false;
        }
        __syncthreads();
        if (ldsinval) break;
        float4 P = ldsbox; float ap = ldsarea;
        if (tid == 0)
            *(float4*)(out + ((size_t)b * NOUT + slot) * 4) = P;
        #pragma unroll
        for (int s = 0; s < 6; ++s) {
            if (!alive[s]) continue;
            float ix1 = fmaxf(P.x, bx[s].x), iy1 = fmaxf(P.y, bx[s].y);
            float ix2 = fminf(P.z, bx[s].z), iy2 = fminf(P.w, bx[s].w);
            float iw = fmaxf(ix2 - ix1, 0.0f), ih = fmaxf(iy2 - iy1, 0.0f);
            float inter = iw * ih;
            float uni = ap + area[s] - inter;
            float iou = (uni > 0.0f) ? (inter / uni) : 0.0f;
            if (iou > 0.7f) alive[s] = false;
        }
        ++nkeep;
        __syncthreads();
    }

    for (int slot = nkeep + tid; slot < NOUT; slot += 1024)
        *(float4*)(out + ((size_t)b * NOUT + slot) * 4) = make_float4(0.f, 0.f, 0.f, 0.f);
}

// ============================================================
extern "C" void kernel_launch(void* const* d_in, const int* in_sizes, int n_in,
                              void* d_out, int out_size, void* d_ws, size_t ws_size,
                              hipStream_t stream) {
    const float* feat   = (const float*)d_in[0];
    const float* conv_w = (const float*)d_in[1];
    const float* conv_b = (const float*)d_in[2];
    const float* cls_w  = (const float*)d_in[3];
    const float* cls_b  = (const float*)d_in[4];
    const float* box_w  = (const float*)d_in[5];
    const float* box_b  = (const float*)d_in[6];

    float* out       = (float*)d_out;
    float* out_props = out;                       // [8][300][4]
    float* out_obj   = out + 9600;                // [8][34200]
    float* out_del   = out + 9600 + 273600;       // [8][34200][4]

    char* ws = (char*)d_ws;
    double* t      = (double*)(ws + OFF_T);
    float*  wt     = (float*)(ws + OFF_WT);
    float*  boxes  = (float*)(ws + OFF_BOXES);
    u64*    items  = (u64*)(ws + OFF_ITEMS);
    u32*    sorted = (u32*)(ws + OFF_SORTED);
    double* part   = (double*)(ws + OFF_PART);

    hipLaunchKernelGGL(wtrans_kernel, dim3(2304), dim3(1024), 0, stream, conv_w, wt);
    hipLaunchKernelGGL(conv3x3_mfma_kernel, dim3(60, 4, 8), dim3(256), 0, stream,
                       feat, wt, conv_b, t);
    if (ws_size >= WS_NEED_SPLIT) {
        hipLaunchKernelGGL(heads_partial_kernel, dim3(60, 8, 4), dim3(64), 0, stream,
                           t, cls_w, box_w, part);
        hipLaunchKernelGGL(reduce_decode_kernel, dim3(60, 8), dim3(64), 0, stream,
                           part, cls_b, box_b, out_obj, out_del, boxes, items);
    } else {
        hipLaunchKernelGGL(heads_decode_kernel, dim3(15, 8), dim3(256), 0, stream,
                           t, cls_w, cls_b, box_w, box_b, out_obj, out_del, boxes, items);
    }
    hipLaunchKernelGGL(topk_kernel, dim3(8), dim3(1024), 65536, stream, items, sorted);
    hipLaunchKernelGGL(nms_kernel, dim3(8), dim3(1024), 0, stream, sorted, boxes, out_props);
}

// Round 7
// 2868.704 us; speedup vs baseline: 1.8014x; 1.3407x over previous
//
#include <hip/hip_runtime.h>
#include <stdint.h>
#include <math.h>

typedef unsigned int u32;
typedef unsigned long long u64;
typedef double d4 __attribute__((ext_vector_type(4)));

#define NPX    3800        // 50*76
#define NANCH  34200       // NPX*9
#define NSEL   6000
#define NOUT   300

// ---- workspace layout (bytes) ----
// t:      [8][512][3800] f64  = 124,518,400
// wt:     [9][512][512]  f32  =   9,437,184
// boxes:  [8][34200][4]  f32  =   4,377,600
// items:  [8][34200]     u64  =   2,188,800
// (gap: old sorted region, unused)     192,000
// part:   [4][8][45][3800] f64 = 43,776,000   (split-K heads, if ws permits)
#define OFF_T      0ull
#define OFF_WT     124518400ull
#define OFF_BOXES  (OFF_WT + 9437184ull)
#define OFF_ITEMS  (OFF_BOXES + 4377600ull)
#define OFF_PART   (OFF_ITEMS + 2188800ull + 192000ull)
#define WS_NEED_SPLIT (OFF_PART + 43776000ull)

// ============================================================
// Kernel 0: weight transpose conv_w[co][ci][ky][kx] -> wt[kk][ci][co]
// ============================================================
__global__ __launch_bounds__(1024) void wtrans_kernel(const float* __restrict__ cw,
                                                      float* __restrict__ wt) {
    int o = blockIdx.x * 1024 + threadIdx.x;
    if (o >= 512*512*9) return;
    int co = o & 511;
    int ci = (o >> 9) & 511;
    int kk = o >> 18;
    wt[o] = cw[((co << 9) + ci) * 9 + kk];
}

// ============================================================
// Kernel 1: 3x3 conv 512->512 + bias + ReLU via f64 MFMA
// tile: 128 co x 64 px, K-chunk 16 ci, 256 thr (4 waves)
// Round-7 structure: A-operand DIRECT global->register (lane-linear,
// L2-resident wt; no LDS round-trip), B in PING-PONG LDS with ONE
// barrier per iteration (round-6 had 2 barriers + vmcnt(0) drain =
// the ~25% MfmaUtil gap). D lane->coord map PROBED at runtime (this
// is what fixed rounds 3/4 -- f64 C/D layout is not the documented one).
// ============================================================
__global__ __launch_bounds__(256, 2) void conv3x3_mfma_kernel(const float* __restrict__ feat,
                                                              const float* __restrict__ wt,
                                                              const float* __restrict__ bias,
                                                              double* __restrict__ t) {
    const int b   = blockIdx.z;
    const int co0 = blockIdx.y << 7;
    const int px0 = blockIdx.x << 6;
    const int tid = threadIdx.x;
    const int w    = tid >> 6;
    const int l    = tid & 63;
    const int quad = l >> 4;
    const int lc   = l & 15;

    __shared__ double BsF[2][1024];   // 16 KB: ping-pong, 16 frags x 64 lanes

    // ---- runtime D-layout probe ----
    int rr[4], cc[4];
    {
        d4 pzr = {0.0, 0.0, 0.0, 0.0};
        d4 pzc = {0.0, 0.0, 0.0, 0.0};
        double paM = (double)lc;
        double pbN = (double)lc;
        pzr = __builtin_amdgcn_mfma_f64_16x16x4f64(paM, 1.0, pzr, 0, 0, 0);
        pzc = __builtin_amdgcn_mfma_f64_16x16x4f64(1.0, pbN, pzc, 0, 0, 0);
        #pragma unroll
        for (int g = 0; g < 4; ++g) {
            rr[g] = (((int)pzr[g]) >> 2) & 15;
            cc[g] = (((int)pzc[g]) >> 2) & 15;
        }
    }

    d4 acc[2][4];
    #pragma unroll
    for (int i = 0; i < 2; ++i)
        #pragma unroll
        for (int j = 0; j < 4; ++j) acc[i][j] = (d4){0.0, 0.0, 0.0, 0.0};

    const float* featb = feat + (size_t)b * 512 * NPX;

    // B staging geometry (HW-verified in round 6):
    //  thread stages ci_local = 4j + b_quad at pixel b_pxl, slot tid + j*256
    const int b_quad = (tid >> 4) & 3;
    const int b_pxl  = ((tid >> 6) << 4) | (tid & 15);
    const int p      = px0 + b_pxl;
    const int py     = p / 76;
    const int px     = p - py * 76;
    const bool pvalid = (p < NPX);

    float vaf[8], vbf[4];
    double a_cur[8];

    // A fragment (ks,mt), lane l: wt[kk][ci0 + 4ks + quad][co0 + w*32 + mt*16 + lc]
    auto loadA = [&](int q, float* va) {
        int kk  = q >> 5;
        int ci0 = (q & 31) << 4;
        const float* ap = wt + (((size_t)(kk * 512 + ci0 + quad)) << 9)
                             + co0 + (w << 5) + lc;
        #pragma unroll
        for (int ks = 0; ks < 4; ++ks) {
            va[ks * 2 + 0] = ap[(ks << 11)];        // mt=0  (ks*4 ci rows * 512)
            va[ks * 2 + 1] = ap[(ks << 11) + 16];   // mt=1
        }
    };
    auto loadB = [&](int q, float* vb) {
        int kk  = q >> 5;
        int ci0 = (q & 31) << 4;
        int kd = kk / 3;
        int dy = kd - 1, dx = kk - kd * 3 - 1;
        int iy = py + dy, ix = px + dx;
        bool ok = pvalid && ((unsigned)iy < 50u) && ((unsigned)ix < 76u);
        if (ok) {
            const float* bp = featb + (size_t)(ci0 + b_quad) * NPX + iy * 76 + ix;
            #pragma unroll
            for (int j = 0; j < 4; ++j) vb[j] = bp[(size_t)(j << 2) * NPX];
        } else {
            vb[0] = vb[1] = vb[2] = vb[3] = 0.0f;
        }
    };

    // prologue
    loadA(0, vaf); loadB(0, vbf);
    #pragma unroll
    for (int j = 0; j < 4; ++j) BsF[0][tid + (j << 8)] = (double)vbf[j];
    #pragma unroll
    for (int j = 0; j < 8; ++j) a_cur[j] = (double)vaf[j];
    __syncthreads();

    for (int q = 0; q < 288; ++q) {
        const int cur = q & 1;
        if (q < 287) { loadA(q + 1, vaf); loadB(q + 1, vbf); }   // in flight under MFMA
        const double* bb = BsF[cur];
        #pragma unroll
        for (int ks = 0; ks < 4; ++ks) {
            const double* bp = bb + (ks << 8);
            double a0 = a_cur[ks * 2], a1 = a_cur[ks * 2 + 1];
            #pragma unroll
            for (int nt = 0; nt < 4; ++nt) {
                double bv = bp[(nt << 6) + l];
                acc[0][nt] = __builtin_amdgcn_mfma_f64_16x16x4f64(a0, bv, acc[0][nt], 0, 0, 0);
                acc[1][nt] = __builtin_amdgcn_mfma_f64_16x16x4f64(a1, bv, acc[1][nt], 0, 0, 0);
            }
        }
        if (q < 287) {
            #pragma unroll
            for (int j = 0; j < 4; ++j) BsF[cur ^ 1][tid + (j << 8)] = (double)vbf[j];
            #pragma unroll
            for (int j = 0; j < 8; ++j) a_cur[j] = (double)vaf[j];
            __syncthreads();   // single barrier: publishes buf cur^1 for iter q+1
        }
    }

    // epilogue: bias + ReLU, store f64, indexed by PROBED (rr,cc)
    #pragma unroll
    for (int mt = 0; mt < 2; ++mt) {
        #pragma unroll
        for (int g = 0; g < 4; ++g) {
            int co = co0 + (w << 5) + (mt << 4) + rr[g];
            double bs = (double)bias[co];
            double* row = t + ((size_t)b * 512 + co) * NPX;
            #pragma unroll
            for (int nt = 0; nt < 4; ++nt) {
                int pp = px0 + (nt << 4) + cc[g];
                if (pp < NPX) {
                    double v = acc[mt][nt][g] + bs;
                    row[pp] = v > 0.0 ? v : 0.0;
                }
            }
        }
    }
}

// ============================================================
// Kernel 2a: 1x1 heads, split-K x4 partials (f64)
// ============================================================
__global__ __launch_bounds__(64) void heads_partial_kernel(const double* __restrict__ t,
                                                           const float* __restrict__ cls_w,
                                                           const float* __restrict__ box_w,
                                                           double* __restrict__ part) {
    const int b = blockIdx.y, c = blockIdx.z;
    const int p = blockIdx.x * 64 + threadIdx.x;
    if (p >= NPX) return;
    const double* tb = t + ((size_t)b * 512 + c * 128) * NPX + p;

    double ac[9]  = {};
    double ab[36] = {};
    for (int ci = 0; ci < 128; ++ci) {
        double tv = tb[(size_t)ci * NPX];
        int cw = c * 128 + ci;
        #pragma unroll
        for (int o = 0; o < 9;  ++o) ac[o] = fma((double)cls_w[o * 512 + cw], tv, ac[o]);
        #pragma unroll
        for (int o = 0; o < 36; ++o) ab[o] = fma((double)box_w[o * 512 + cw], tv, ab[o]);
    }
    double* dst = part + ((size_t)(c * 8 + b) * 45) * NPX + p;
    #pragma unroll
    for (int o = 0; o < 9;  ++o) dst[(size_t)o * NPX] = ac[o];
    #pragma unroll
    for (int o = 0; o < 36; ++o) dst[(size_t)(9 + o) * NPX] = ab[o];
}

// shared decode body
__device__ __forceinline__ void decode_px(int b, int p, const double* s45,
                                          const float* cls_b, const float* box_b,
                                          float* out_obj, float* out_del,
                                          float* boxes, u64* items) {
    float* ob = out_obj + (size_t)b * NANCH + (size_t)p * 9;
    float* dl = out_del + (size_t)b * NANCH * 4 + (size_t)p * 36;
    const int yy = p / 76, xx = p - yy * 76;

    #pragma unroll
    for (int a = 0; a < 9; ++a) {
        double s  = s45[a] + (double)cls_b[a];
        ob[a] = (float)s;
        double d0 = s45[9 + 4*a + 0] + (double)box_b[4*a+0];
        double d1 = s45[9 + 4*a + 1] + (double)box_b[4*a+1];
        double d2 = s45[9 + 4*a + 2] + (double)box_b[4*a+2];
        double d3 = s45[9 + 4*a + 3] + (double)box_b[4*a+3];
        dl[4*a+0] = (float)d0; dl[4*a+1] = (float)d1;
        dl[4*a+2] = (float)d2; dl[4*a+3] = (float)d3;

        int si = a / 3, ri = a - si * 3;
        double sz = (si == 0) ? 128.0 : ((si == 1) ? 256.0 : 512.0);
        double hr = (ri == 0) ? 0.7071067811865476 : ((ri == 1) ? 1.0 : 1.4142135623730951);
        float bx2f = (float)(sz / hr * 0.5);
        float by2f = (float)(sz * hr * 0.5);

        double sx = (double)(xx * 16), sy = (double)(yy * 16);
        double x1 = sx - (double)bx2f, x2 = sx + (double)bx2f;
        double y1 = sy - (double)by2f, y2 = sy + (double)by2f;

        double wa = x2 - x1, ha = y2 - y1;
        double cxa = x1 + 0.5 * wa, cya = y1 + 0.5 * ha;
        double cx = d0 * wa + cxa, cy = d1 * ha + cya;
        double w  = exp(d2) * wa,  h  = exp(d3) * ha;

        double px1 = cx - 0.5 * w, py1 = cy - 0.5 * h;
        double px2 = cx + 0.5 * w, py2 = cy + 0.5 * h;
        px1 = fmin(fmax(px1, 0.0), 1216.0);
        py1 = fmin(fmax(py1, 0.0), 800.0);
        px2 = fmin(fmax(px2, 0.0), 1216.0);
        py2 = fmin(fmax(py2, 0.0), 800.0);

        bool keep = ((px2 - px1) >= 16.0) && ((py2 - py1) >= 16.0);
        double se = keep ? s : -INFINITY;

        u64 ubits = (u64)__double_as_longlong(se);
        u64 ka = (ubits >> 63) ? ~ubits : (ubits | 0x8000000000000000ull);
        u64 kd = ~ka;
        int n = p * 9 + a;
        items[(size_t)b * NANCH + n] = (kd & ~0xFFFFull) | (u64)(u32)n;
        *(float4*)(boxes + ((size_t)b * NANCH + n) * 4) =
            make_float4((float)px1, (float)py1, (float)px2, (float)py2);
    }
}

// ============================================================
// Kernel 2b: reduce partials (c ascending, deterministic) + decode
// ============================================================
__global__ __launch_bounds__(64) void reduce_decode_kernel(const double* __restrict__ part,
                                                           const float* __restrict__ cls_b,
                                                           const float* __restrict__ box_b,
                                                           float* __restrict__ out_obj,
                                                           float* __restrict__ out_del,
                                                           float* __restrict__ boxes,
                                                           u64* __restrict__ items) {
    const int b = blockIdx.y;
    const int p = blockIdx.x * 64 + threadIdx.x;
    if (p >= NPX) return;
    double s45[45];
    #pragma unroll
    for (int o = 0; o < 45; ++o) {
        double s = part[((size_t)(0 * 8 + b) * 45 + o) * NPX + p];
        s += part[((size_t)(1 * 8 + b) * 45 + o) * NPX + p];
        s += part[((size_t)(2 * 8 + b) * 45 + o) * NPX + p];
        s += part[((size_t)(3 * 8 + b) * 45 + o) * NPX + p];
        s45[o] = s;
    }
    decode_px(b, p, s45, cls_b, box_b, out_obj, out_del, boxes, items);
}

// ============================================================
// Kernel 2-fallback: single-stage heads+decode (if ws too small)
// ============================================================
__global__ __launch_bounds__(256) void heads_decode_kernel(const double* __restrict__ t,
                                                           const float* __restrict__ cls_w,
                                                           const float* __restrict__ cls_b,
                                                           const float* __restrict__ box_w,
                                                           const float* __restrict__ box_b,
                                                           float* __restrict__ out_obj,
                                                           float* __restrict__ out_del,
                                                           float* __restrict__ boxes,
                                                           u64* __restrict__ items) {
    const int b = blockIdx.y;
    const int p = blockIdx.x * 256 + threadIdx.x;
    if (p >= NPX) return;
    const double* tb = t + (size_t)b * 512 * NPX + p;
    double s45[45];
    #pragma unroll
    for (int o = 0; o < 45; ++o) s45[o] = 0.0;
    for (int ci = 0; ci < 512; ++ci) {
        double tv = tb[(size_t)ci * NPX];
        #pragma unroll
        for (int o = 0; o < 9;  ++o) s45[o]     = fma((double)cls_w[o * 512 + ci], tv, s45[o]);
        #pragma unroll
        for (int o = 0; o < 36; ++o) s45[9 + o] = fma((double)box_w[o * 512 + ci], tv, s45[9 + o]);
    }
    decode_px(b, p, s45, cls_b, box_b, out_obj, out_del, boxes, items);
}

// ============================================================
// IoU > 0.7 test (f32, matches reference formula)
// ============================================================
__device__ __forceinline__ bool iou_gt(float4 A, float4 B, float areaA, float areaB) {
    float ix1 = fmaxf(A.x, B.x), iy1 = fmaxf(A.y, B.y);
    float ix2 = fminf(A.z, B.z), iy2 = fminf(A.w, B.w);
    float iw = fmaxf(ix2 - ix1, 0.0f), ih = fmaxf(iy2 - iy1, 0.0f);
    float inter = iw * ih;
    float uni = areaA + areaB - inter;
    float iou = (uni > 0.0f) ? (inter / uni) : 0.0f;
    return iou > 0.7f;
}

// ============================================================
// Kernel 3: fused top-6000 select + bitonic sort + serial-scan NMS
// (round-3 logic -- exonerated by round-4 bisection: identical absmax
//  with/without it; conv was the sole culprit)
// ============================================================
__global__ __launch_bounds__(1024) void topk_nms_kernel(const u64* __restrict__ items,
                                                        const float* __restrict__ boxes,
                                                        float* __restrict__ out) {
    extern __shared__ u64 buf[];              // 8192 u64
    u32* hist = (u32*)buf;
    u32* scan = hist + 4096;
    u32* scal = hist + 5120;

    const int b   = blockIdx.x;
    const int tid = threadIdx.x;
    const u64* it = items + (size_t)b * NANCH;

    // ---- level-1 histogram on item bits 52..63
    #pragma unroll
    for (int i = 0; i < 4; ++i) hist[tid * 4 + i] = 0;
    __syncthreads();
    for (int i = tid; i < NANCH; i += 1024)
        atomicAdd(&hist[(u32)(it[i] >> 52)], 1);
    __syncthreads();

    u32 B1, cum1;
    {
        u32 c0 = hist[tid*4], c1 = hist[tid*4+1], c2 = hist[tid*4+2], c3 = hist[tid*4+3];
        u32 S = c0 + c1 + c2 + c3;
        scan[tid] = S;
        __syncthreads();
        for (int off = 1; off < 1024; off <<= 1) {
            u32 v = (tid >= off) ? scan[tid - off] : 0;
            __syncthreads();
            scan[tid] += v;
            __syncthreads();
        }
        u32 excl = scan[tid] - S;
        const u32 target = 5999;
        if (target >= excl && target < excl + S) {
            u32 pfx = excl, bidx, cum;
            if      (target < pfx + c0)           { bidx = tid*4;   cum = pfx; }
            else if (target < pfx + c0 + c1)      { bidx = tid*4+1; cum = pfx + c0; }
            else if (target < pfx + c0 + c1 + c2) { bidx = tid*4+2; cum = pfx + c0 + c1; }
            else                                  { bidx = tid*4+3; cum = pfx + c0 + c1 + c2; }
            scal[0] = bidx; scal[1] = cum;
        }
    }
    __syncthreads();
    B1 = scal[0]; cum1 = scal[1];
    __syncthreads();

    // ---- level-2 histogram on item bits 40..51, within bin B1
    #pragma unroll
    for (int i = 0; i < 4; ++i) hist[tid * 4 + i] = 0;
    __syncthreads();
    for (int i = tid; i < NANCH; i += 1024) {
        u64 v = it[i];
        if ((u32)(v >> 52) == B1)
            atomicAdd(&hist[(u32)(v >> 40) & 0xFFF], 1);
    }
    __syncthreads();

    u32 B2;
    {
        u32 c0 = hist[tid*4], c1 = hist[tid*4+1], c2 = hist[tid*4+2], c3 = hist[tid*4+3];
        u32 S = c0 + c1 + c2 + c3;
        scan[tid] = S;
        __syncthreads();
        for (int off = 1; off < 1024; off <<= 1) {
            u32 v = (tid >= off) ? scan[tid - off] : 0;
            __syncthreads();
            scan[tid] += v;
            __syncthreads();
        }
        u32 excl = scan[tid] - S;
        const u32 target = 5999 - cum1;
        if (target >= excl && target < excl + S) {
            u32 pfx = excl, bidx;
            if      (target < pfx + c0)           bidx = tid*4;
            else if (target < pfx + c0 + c1)      bidx = tid*4+1;
            else if (target < pfx + c0 + c1 + c2) bidx = tid*4+2;
            else                                  bidx = tid*4+3;
            scal[2] = bidx;
        }
    }
    __syncthreads();
    B2 = scal[2];
    const u32 T = ((B1 << 12) | B2) + 1;
    __syncthreads();

    // ---- compaction (pad = ~0)
    for (int i = tid; i < 8192; i += 1024) buf[i] = ~0ull;
    __syncthreads();
    u32* cnt = (u32*)&buf[8191];
    if (tid == 0) *cnt = 0;
    __syncthreads();
    for (int i = tid; i < NANCH; i += 1024) {
        u64 v = it[i];
        if ((u32)(v >> 40) < T) {
            u32 pos = atomicAdd(cnt, 1);
            if (pos < 8191) buf[pos] = v;
        }
    }
    __syncthreads();
    if (tid == 0) buf[8191] = ~0ull;
    __syncthreads();

    // ---- bitonic sort 8192 u64 ascending (keys unique -> deterministic)
    for (int size = 2; size <= 8192; size <<= 1) {
        for (int stride = size >> 1; stride > 0; stride >>= 1) {
            #pragma unroll
            for (int v = 0; v < 4; ++v) {
                int idx = tid + (v << 10);
                int i = 2 * idx - (idx & (stride - 1));
                int j = i + stride;
                bool up = ((i & size) == 0);
                u64 x = buf[i], y = buf[j];
                if ((x > y) == up) { buf[i] = y; buf[j] = x; }
            }
            __syncthreads();
        }
    }

    // ---- pull my 6 chunk-candidates into registers
    float4 bx6[6]; u32 dead6[6];
    #pragma unroll
    for (int s = 0; s < 6; ++s) {
        int r = tid + (s << 10);
        u64 v = buf[r];
        bool dd = (r >= NSEL) || ((u32)(v >> 32) >= 0xFFF00000u);
        float4 bb = make_float4(0.f, 0.f, 0.f, 0.f);
        if (!dd) {
            u32 n = (u32)(v & 0xFFFFull);
            bb = *(const float4*)(boxes + ((size_t)b * NANCH + n) * 4);
        }
        bx6[s] = bb;
        dead6[s] = dd ? 1u : 0u;
    }
    __syncthreads();   // done with sorted buf -> reuse as NMS scratch

    float4* candbox = (float4*)buf;            // [1024]  16 KB
    u64*    wmask   = (u64*)(buf + 2560);      // [16]
    float4* accb    = (float4*)(buf + 3072);   // [304]
    u32*    cntp    = (u32*)(buf + 3712);
    if (tid == 0) *cntp = 0;
    __syncthreads();

    // ---- serial-scan greedy NMS (accept iff no earlier accept IoU>0.7)
    for (int s = 0; s < 6; ++s) {
        int count = (int)*cntp;                // uniform
        if (count >= NOUT) break;
        float4 mb = bx6[s];
        float  ma = (mb.z - mb.x) * (mb.w - mb.y);
        bool dd = dead6[s] != 0;
        for (int a2 = 0; a2 < count && !dd; ++a2) {
            float4 abx = accb[a2];             // broadcast read
            if (iou_gt(mb, abx, ma, (abx.z - abx.x) * (abx.w - abx.y))) dd = true;
        }
        candbox[tid] = mb;
        u64 bal = __ballot(!dd);
        if ((tid & 63) == 0) wmask[tid >> 6] = bal;
        __syncthreads();
        if (tid < 64) {                        // wave 0 serializes survivors in rank order
            int cnt2 = count;
            for (int w2 = 0; w2 < 16 && cnt2 < NOUT; ++w2) {
                u64 mm = wmask[w2];
                while (mm != 0 && cnt2 < NOUT) {
                    int bit = __ffsll(mm) - 1;
                    mm &= (mm - 1);
                    float4 cb = candbox[(w2 << 6) + bit];
                    float  ca = (cb.z - cb.x) * (cb.w - cb.y);
                    bool okc = true;
                    for (int base = count; base < cnt2 && okc; base += 64) {
                        int idx = base + tid;
                        bool bad = false;
                        if (idx < cnt2) {
                            float4 abx = accb[idx];
                            bad = iou_gt(cb, abx, ca, (abx.z - abx.x) * (abx.w - abx.y));
                        }
                        if (__any(bad)) okc = false;
                    }
                    if (okc) {
                        if (tid == 0) accb[cnt2] = cb;
                        cnt2++;
                    }
                }
            }
            if (tid == 0) *cntp = (u32)cnt2;
        }
        __syncthreads();
    }

    int fin = (int)*cntp;
    for (int r = tid; r < NOUT; r += 1024) {
        float4 v = (r < fin) ? accb[r] : make_float4(0.f, 0.f, 0.f, 0.f);
        *(float4*)(out + ((size_t)b * NOUT + r) * 4) = v;
    }
}

// ============================================================
extern "C" void kernel_launch(void* const* d_in, const int* in_sizes, int n_in,
                              void* d_out, int out_size, void* d_ws, size_t ws_size,
                              hipStream_t stream) {
    const float* feat   = (const float*)d_in[0];
    const float* conv_w = (const float*)d_in[1];
    const float* conv_b = (const float*)d_in[2];
    const float* cls_w  = (const float*)d_in[3];
    const float* cls_b  = (const float*)d_in[4];
    const float* box_w  = (const float*)d_in[5];
    const float* box_b  = (const float*)d_in[6];

    float* out       = (float*)d_out;
    float* out_props = out;                       // [8][300][4]
    float* out_obj   = out + 9600;                // [8][34200]
    float* out_del   = out + 9600 + 273600;       // [8][34200][4]

    char* ws = (char*)d_ws;
    double* t      = (double*)(ws + OFF_T);
    float*  wt     = (float*)(ws + OFF_WT);
    float*  boxes  = (float*)(ws + OFF_BOXES);
    u64*    items  = (u64*)(ws + OFF_ITEMS);
    double* part   = (double*)(ws + OFF_PART);

    hipLaunchKernelGGL(wtrans_kernel, dim3(2304), dim3(1024), 0, stream, conv_w, wt);
    hipLaunchKernelGGL(conv3x3_mfma_kernel, dim3(60, 4, 8), dim3(256), 0, stream,
                       feat, wt, conv_b, t);
    if (ws_size >= WS_NEED_SPLIT) {
        hipLaunchKernelGGL(heads_partial_kernel, dim3(60, 8, 4), dim3(64), 0, stream,
                           t, cls_w, box_w, part);
        hipLaunchKernelGGL(reduce_decode_kernel, dim3(60, 8), dim3(64), 0, stream,
                           part, cls_b, box_b, out_obj, out_del, boxes, items);
    } else {
        hipLaunchKernelGGL(heads_decode_kernel, dim3(15, 8), dim3(256), 0, stream,
                           t, cls_w, cls_b, box_w, box_b, out_obj, out_del, boxes, items);
    }
    hipLaunchKernelGGL(topk_nms_kernel, dim3(8), dim3(1024), 65536, stream,
                       items, boxes, out_props);
}